// Round 6
// baseline (107.910 us; speedup 1.0000x reference)
//
#include <hip/hip_runtime.h>

// GNN_module: patch-conv -> deformable 27-tap sampling -> per-pixel attention -> up+1x1 conv
// T=8, H=W=24, C=256, K=27, J=216
// R6: final GEMM fused into k_attn epilogue (3 kernels total).

typedef unsigned short ushort_t;
typedef ushort_t ushort8 __attribute__((ext_vector_type(8)));
typedef __bf16 bf16x8 __attribute__((ext_vector_type(8)));
typedef __bf16 bf16x2 __attribute__((ext_vector_type(2)));
typedef float f32x4 __attribute__((ext_vector_type(4)));
typedef unsigned int uint4v __attribute__((ext_vector_type(4)));

#define NSTR 264   // neigh row stride (ushorts)
#define TSTR 34    // neighT row stride (ushorts)
#define ASTR 40    // A_s row stride (ushorts)

// dynamic-LDS byte offsets for k_attn
#define OFF_NH0   0
#define OFF_NH1   16896
#define OFF_NT0   33792
#define OFF_NT1   51200
#define OFF_AS    68608
#define OFF_BASES 69888
#define OFF_WTS   73472
#define ATTN_LDS  77056

__device__ __forceinline__ ushort_t f2bf(float f) {
    __bf16 h = (__bf16)f;
    return __builtin_bit_cast(ushort_t, h);
}
__device__ __forceinline__ float blo(unsigned u) { return __uint_as_float(u << 16); }
__device__ __forceinline__ float bhi(unsigned u) { return __uint_as_float(u & 0xffff0000u); }
__device__ __forceinline__ unsigned pk2(float a, float b) {
    bf16x2 v = { (__bf16)a, (__bf16)b };
    return __builtin_bit_cast(unsigned, v);
}
__device__ __forceinline__ unsigned pk2h(__bf16 a, __bf16 b) {
    bf16x2 v = { a, b };
    return __builtin_bit_cast(unsigned, v);
}
__device__ __forceinline__ void gld_lds16(const void* g, void* l) {
    __builtin_amdgcn_global_load_lds(
        (const __attribute__((address_space(1))) unsigned*)g,
        (__attribute__((address_space(3))) unsigned*)l, 16, 0, 0);
}

// ---------------------------------------------------------------- prep -------
__global__ __launch_bounds__(256) void k_prep(
    const float* __restrict__ w_node, const float* __restrict__ w_up,
    const float* __restrict__ w_out, const float* __restrict__ b_up,
    const float* __restrict__ b_out,
    ushort_t* __restrict__ w_node_perm, ushort_t* __restrict__ Wf_perm,
    float* __restrict__ bias_tot)
{
    __shared__ float wout_s[4096];
    int tid = threadIdx.x;
    for (int i = tid; i < 4096; i += 256) wout_s[i] = w_out[i];
    __syncthreads();
    int gid = blockIdx.x * 256 + tid;
    #pragma unroll
    for (int r = 0; r < 4; ++r) {
        int e = gid + r * 65536;
        {
            int k = e & 1023, n = e >> 10;
            w_node_perm[(((k >> 3) << 8) + n) * 8 + (k & 7)] = f2bf(w_node[n * 1024 + k]);
        }
        {
            int n = e & 1023, k = e >> 10;
            int o = n >> 4, ab = n & 15;
            const float* wo = wout_s + o * 64;
            const float* wu = w_up + (k << 10) + ab;
            float s = 0.f;
            #pragma unroll 8
            for (int c = 0; c < 64; ++c) s += wo[c] * wu[c << 4];
            Wf_perm[(((k >> 3) << 10) + n) * 8 + (k & 7)] = f2bf(s);
        }
    }
    if (blockIdx.x == 0 && tid < 64) {
        float s = b_out[tid];
        const float* wo = wout_s + tid * 64;
        #pragma unroll 8
        for (int c = 0; c < 64; ++c) s += wo[c] * b_up[c];
        bias_tot[tid] = s;
    }
}

// ------------------------------------------------------------ node GEMM ------
// BM=32, BN=64, BK=64; 256 threads = 4 waves; M=4608,K=1024,N=256
__global__ __launch_bounds__(256) void k_gemm0(
    const float* __restrict__ input, const ushort_t* __restrict__ w_perm,
    const float* __restrict__ bias, ushort_t* __restrict__ node_bf)
{
    constexpr int KS = 16;
    constexpr int N  = 256;
    constexpr int BN = 64;
    __shared__ __align__(16) ushort_t A_lds[2][2048];
    __shared__ __align__(16) ushort_t B_lds[2][BN * 64];
    int tid  = threadIdx.x;
    int lane = tid & 63, wid = tid >> 6;
    int g = lane >> 4, r16 = lane & 15;
    int m0 = blockIdx.x * 32, n0 = blockIdx.y * BN;

    int mA = tid & 31, kcA = tid >> 5;
    int m = m0 + mA;
    int t = m / 576, hw = m % 576, hh = hw / 24, ww = hw % 24;
    const float* inpA = input + (size_t)(kcA >> 1) * 73728 + t * 9216 + hh * 384 + ww * 4 + (kcA & 1) * 192;
    int ldsA_slot = (kcA * 32 + mA) * 8;

    f32x4 acc[2];
    acc[0] = (f32x4){0.f, 0.f, 0.f, 0.f};
    acc[1] = (f32x4){0.f, 0.f, 0.f, 0.f};

    float4 fa, fb;
    #pragma unroll
    for (int r = 0; r < 2; ++r) {
        int s = r * 256 + tid;
        int kc = s / BN, n = s % BN;
        gld_lds16(w_perm + (size_t)((kc * N + n0 + n) * 8), &B_lds[0][s * 8]);
    }
    fa = *(const float4*)(inpA);
    fb = *(const float4*)(inpA + 96);
    {
        uint4v p;
        p.x = pk2(fa.x, fa.y); p.y = pk2(fa.z, fa.w);
        p.z = pk2(fb.x, fb.y); p.w = pk2(fb.z, fb.w);
        *(uint4v*)&A_lds[0][ldsA_slot] = p;
    }
    __syncthreads();

    for (int kb = 0; kb < KS; ++kb) {
        int cur = kb & 1, nxt = cur ^ 1;
        bool more = (kb + 1 < KS);
        if (more) {
            #pragma unroll
            for (int r = 0; r < 2; ++r) {
                int s = r * 256 + tid;
                int kc = s / BN, n = s % BN;
                gld_lds16(w_perm + (size_t)((((kb + 1) * 8 + kc) * N + n0 + n) * 8),
                          &B_lds[nxt][s * 8]);
            }
            fa = *(const float4*)(inpA + (size_t)(kb + 1) * 294912);
            fb = *(const float4*)(inpA + (size_t)(kb + 1) * 294912 + 96);
        }
        bf16x8 af[2][2], bfr[2];
        #pragma unroll
        for (int mi = 0; mi < 2; ++mi)
            #pragma unroll
            for (int ks = 0; ks < 2; ++ks) {
                int idx = ((ks * 4 + g) * 32 + mi * 16 + r16) * 8;
                af[mi][ks] = __builtin_bit_cast(bf16x8, *(const ushort8*)&A_lds[cur][idx]);
            }
        #pragma unroll
        for (int ks = 0; ks < 2; ++ks) {
            int idx = ((ks * 4 + g) * BN + wid * 16 + r16) * 8;
            bfr[ks] = __builtin_bit_cast(bf16x8, *(const ushort8*)&B_lds[cur][idx]);
        }
        #pragma unroll
        for (int mi = 0; mi < 2; ++mi)
            #pragma unroll
            for (int ks = 0; ks < 2; ++ks)
                acc[mi] = __builtin_amdgcn_mfma_f32_16x16x32_bf16(
                    af[mi][ks], bfr[ks], acc[mi], 0, 0, 0);
        if (more) {
            uint4v p;
            p.x = pk2(fa.x, fa.y); p.y = pk2(fa.z, fa.w);
            p.z = pk2(fb.x, fb.y); p.w = pk2(fb.z, fb.w);
            *(uint4v*)&A_lds[nxt][ldsA_slot] = p;
        }
        __syncthreads();
    }

    int n = n0 + wid * 16 + r16;
    float bv = bias[n];
    #pragma unroll
    for (int mi = 0; mi < 2; ++mi)
        #pragma unroll
        for (int rr = 0; rr < 4; ++rr) {
            int mm = m0 + mi * 16 + 4 * g + rr;
            node_bf[(size_t)mm * 256 + n] = f2bf(acc[mi][rr] + bv);
        }
}

// ------------------------------------------ attention + fused final GEMM -----
// One block per position, 4 waves, double-buffered 32-j tiles, 2 barriers/tile:
//   P1: A-GEMM(k) | P2: out-GEMM(k) || combine(k+1) || prefetch(k+2)
// Epilogue: out[8][256] -> LDS (swizzled) -> 16x16x32 MFMA vs Wf (global B) -> dout
__global__ __launch_bounds__(256) void k_attn(
    const ushort_t* __restrict__ node_bf, const float* __restrict__ flow,
    const ushort_t* __restrict__ wf_p, const float* __restrict__ bias_t,
    float* __restrict__ dout)
{
    extern __shared__ char smem[];
    ushort_t* A_s   = (ushort_t*)(smem + OFF_AS);
    int*      bases = (int*)(smem + OFF_BASES);
    float*    wts   = (float*)(smem + OFF_WTS);

    int tid  = threadIdx.x;
    int pos  = blockIdx.x;
    int h    = pos / 24, w = pos % 24;
    int lane = tid & 63, wid = tid >> 6;
    int g    = lane >> 4, r16 = lane & 15;

    if (tid < 224) {
        int j = tid;
        float w00 = 0, w01 = 0, w10 = 0, w11 = 0;
        int b00 = 0, b01 = 0, b10 = 0, b11 = 0;
        if (j < 216) {
            int tt = j / 27, kk = j - tt * 27;
            int d  = 2 * (kk / 9) + 1;
            int oy = (kk / 3) % 3 - 1, ox = kk % 3 - 1;
            float fy = flow[tt * 576 + pos];
            float fx = flow[4608 + tt * 576 + pos];
            float py = (float)(h + oy * d) + fy;
            float px = (float)(w + ox * d) + fx;
            float fy0 = floorf(py), fx0 = floorf(px);
            int y0 = (int)fy0, x0 = (int)fx0;
            float ty = py - fy0, tx = px - fx0;
            int y0c = min(max(y0, 0), 23), y1c = min(max(y0 + 1, 0), 23);
            int x0c = min(max(x0, 0), 23), x1c = min(max(x0 + 1, 0), 23);
            float vy0 = (y0 >= 0 && y0 < 24) ? 1.f : 0.f;
            float vy1 = (y0 >= -1 && y0 < 23) ? 1.f : 0.f;
            float vx0 = (x0 >= 0 && x0 < 24) ? 1.f : 0.f;
            float vx1 = (x0 >= -1 && x0 < 23) ? 1.f : 0.f;
            w00 = (1.f - ty) * (1.f - tx) * vy0 * vx0;
            w01 = (1.f - ty) * tx * vy0 * vx1;
            w10 = ty * (1.f - tx) * vy1 * vx0;
            w11 = ty * tx * vy1 * vx1;
            int base_t = tt * 576 * 256;
            b00 = base_t + (y0c * 24 + x0c) * 256;
            b01 = base_t + (y0c * 24 + x1c) * 256;
            b10 = base_t + (y1c * 24 + x0c) * 256;
            b11 = base_t + (y1c * 24 + x1c) * 256;
        }
        bases[j * 4 + 0] = b00; bases[j * 4 + 1] = b01;
        bases[j * 4 + 2] = b10; bases[j * 4 + 3] = b11;
        wts[j * 4 + 0] = w00; wts[j * 4 + 1] = w01;
        wts[j * 4 + 2] = w10; wts[j * 4 + 3] = w11;
    }
    for (int i = tid; i < 320; i += 256) ((unsigned*)A_s)[i] = 0;

    bf16x8 nbf[8];
    if (wid < 2) {
        int t = r16;
        const ushort_t* src = node_bf + ((size_t)(t & 7) * 576 + pos) * 256 + g * 8;
        ushort8 uz = {};
        #pragma unroll
        for (int s = 0; s < 8; ++s) {
            ushort8 uu = *(const ushort8*)(src + s * 32);
            nbf[s] = __builtin_bit_cast(bf16x8, (t < 8) ? uu : uz);
        }
    }

    f32x4 oacc[4];
    #pragma unroll
    for (int i = 0; i < 4; ++i) oacc[i] = (f32x4){0.f, 0.f, 0.f, 0.f};

    __syncthreads();                             // bases/wts visible

    const int jp = tid >> 4;
    const int cb = tid & 15;
    uint4v rg[2][8];

    auto prefetch = [&](int TILE) {
        int jA = TILE * 32 + jp * 2;
        int4 bsA = *(const int4*)&bases[jA * 4];
        int4 bsB = *(const int4*)&bases[jA * 4 + 4];
        #pragma unroll
        for (int q = 0; q < 2; ++q) {
            int c0 = cb * 16 + q * 8;
            rg[q][0] = *(const uint4v*)(node_bf + bsA.x + c0);
            rg[q][1] = *(const uint4v*)(node_bf + bsA.y + c0);
            rg[q][2] = *(const uint4v*)(node_bf + bsA.z + c0);
            rg[q][3] = *(const uint4v*)(node_bf + bsA.w + c0);
            rg[q][4] = *(const uint4v*)(node_bf + bsB.x + c0);
            rg[q][5] = *(const uint4v*)(node_bf + bsB.y + c0);
            rg[q][6] = *(const uint4v*)(node_bf + bsB.z + c0);
            rg[q][7] = *(const uint4v*)(node_bf + bsB.w + c0);
        }
    };
    auto combine = [&](int TILE, ushort_t* nh, ushort_t* nt) {
        int jA = TILE * 32 + jp * 2;
        int jl = jp * 2;
        float4 wA = *(const float4*)&wts[jA * 4];
        float4 wB = *(const float4*)&wts[jA * 4 + 4];
        #pragma unroll
        for (int q = 0; q < 2; ++q) {
            int c0 = cb * 16 + q * 8;
            uint4v outA, outB;
            #pragma unroll
            for (int p = 0; p < 4; ++p) {
                unsigned a0 = rg[q][0][p], a1 = rg[q][1][p], a2 = rg[q][2][p], a3 = rg[q][3][p];
                unsigned b0 = rg[q][4][p], b1 = rg[q][5][p], b2 = rg[q][6][p], b3 = rg[q][7][p];
                float aL = wA.x * blo(a0) + wA.y * blo(a1) + wA.z * blo(a2) + wA.w * blo(a3);
                float aH = wA.x * bhi(a0) + wA.y * bhi(a1) + wA.z * bhi(a2) + wA.w * bhi(a3);
                float bL = wB.x * blo(b0) + wB.y * blo(b1) + wB.z * blo(b2) + wB.w * blo(b3);
                float bH = wB.x * bhi(b0) + wB.y * bhi(b1) + wB.z * bhi(b2) + wB.w * bhi(b3);
                __bf16 cAL = (__bf16)aL, cAH = (__bf16)aH;
                __bf16 cBL = (__bf16)bL, cBH = (__bf16)bH;
                outA[p] = pk2h(cAL, cAH);
                outB[p] = pk2h(cBL, cBH);
                *(unsigned*)(nt + (c0 + 2 * p) * TSTR + jl)     = pk2h(cAL, cBL);
                *(unsigned*)(nt + (c0 + 2 * p + 1) * TSTR + jl) = pk2h(cAH, cBH);
            }
            *(uint4v*)(nh + jl * NSTR + c0)       = outA;
            *(uint4v*)(nh + (jl + 1) * NSTR + c0) = outB;
        }
    };

    prefetch(0);
    combine(0, (ushort_t*)(smem + OFF_NH0), (ushort_t*)(smem + OFF_NT0));
    prefetch(1);
    __syncthreads();

    for (int k = 0; k < 7; ++k) {
        int cur = k & 1;
        ushort_t* nh = (ushort_t*)(smem + (cur ? OFF_NH1 : OFF_NH0));
        ushort_t* nt = (ushort_t*)(smem + (cur ? OFF_NT1 : OFF_NT0));

        if (wid < 2) {
            f32x4 aacc = {0.f, 0.f, 0.f, 0.f};
            int jbase = wid * 16;
            #pragma unroll
            for (int s = 0; s < 8; ++s) {
                const ushort_t* bp = nh + (jbase + r16) * NSTR + s * 32 + g * 8;
                bf16x8 bfrag = __builtin_bit_cast(bf16x8, *(const ushort8*)bp);
                aacc = __builtin_amdgcn_mfma_f32_16x16x32_bf16(nbf[s], bfrag, aacc, 0, 0, 0);
            }
            if (g < 2) {
                #pragma unroll
                for (int rr = 0; rr < 4; ++rr)
                    A_s[(4 * g + rr) * ASTR + jbase + r16] = f2bf(aacc[rr] * (1.f / 216.f));
            }
        }
        __syncthreads();

        {
            bf16x8 afrag = __builtin_bit_cast(bf16x8, *(const ushort8*)(A_s + r16 * ASTR + g * 8));
            #pragma unroll
            for (int i = 0; i < 4; ++i) {
                const ushort_t* tp = nt + (wid * 64 + i * 16 + r16) * TSTR + g * 8;
                uint4v uv;
                uv.x = *(const unsigned*)(tp);
                uv.y = *(const unsigned*)(tp + 2);
                uv.z = *(const unsigned*)(tp + 4);
                uv.w = *(const unsigned*)(tp + 6);
                bf16x8 bfrag = __builtin_bit_cast(bf16x8, uv);
                oacc[i] = __builtin_amdgcn_mfma_f32_16x16x32_bf16(afrag, bfrag, oacc[i], 0, 0, 0);
            }
        }
        if (k < 6) {
            ushort_t* nh2 = (ushort_t*)(smem + (cur ? OFF_NH0 : OFF_NH1));
            ushort_t* nt2 = (ushort_t*)(smem + (cur ? OFF_NT0 : OFF_NT1));
            combine(k + 1, nh2, nt2);
            if (k <= 4) prefetch(k + 2);
        }
        __syncthreads();
    }

    // ---- fused final GEMM epilogue ------------------------------------------
    // Stage out rows to LDS (reuse NH1 region; rows 8..15 stay garbage — MFMA
    // rows are independent and those D-rows are never stored).
    ushort_t* out_s = (ushort_t*)(smem + OFF_NH1);   // [16][256] bf16, swizzled
    if (g < 2) {
        #pragma unroll
        for (int i = 0; i < 4; ++i) {
            int c = wid * 64 + i * 16 + r16;
            #pragma unroll
            for (int rr = 0; rr < 4; ++rr) {
                int t = 4 * g + rr;
                out_s[t * 256 + (c ^ ((t & 7) << 3))] = f2bf(oacc[i][rr]);
            }
        }
    }
    __syncthreads();

    // A-fragments: af[ks], lane(g,r16) holds out[row=r16][k = ks*32+g*8 .. +7]
    bf16x8 af[8];
    #pragma unroll
    for (int ks = 0; ks < 8; ++ks) {
        int e = r16 * 256 + ((ks * 32 + g * 8) ^ ((r16 & 7) << 3));
        af[ks] = __builtin_bit_cast(bf16x8, *(const ushort8*)(out_s + e));
    }

    int aa = r16 >> 2, bb = r16 & 3;
    #pragma unroll 2
    for (int nf = 0; nf < 16; ++nf) {
        f32x4 bacc = {0.f, 0.f, 0.f, 0.f};
        const ushort_t* wp = wf_p + (size_t)(wid * 256 + nf * 16 + r16) * 8 + (size_t)g * 8192;
        #pragma unroll
        for (int ks = 0; ks < 8; ++ks) {
            bf16x8 bfr = __builtin_bit_cast(bf16x8, *(const ushort8*)(wp + (size_t)ks * 32768));
            bacc = __builtin_amdgcn_mfma_f32_16x16x32_bf16(af[ks], bfr, bacc, 0, 0, 0);
        }
        if (g < 2) {
            int o = wid * 16 + nf;
            float bv = bias_t[o];
            #pragma unroll
            for (int rr = 0; rr < 4; ++rr) {
                int t = 4 * g + rr;
                dout[((size_t)(o * 8 + t) * 96 + h * 4 + aa) * 96 + w * 4 + bb] = bacc[rr] + bv;
            }
        }
    }
}

// ----------------------------------------------------------------------------
extern "C" void kernel_launch(void* const* d_in, const int* in_sizes, int n_in,
                              void* d_out, int out_size, void* d_ws, size_t ws_size,
                              hipStream_t stream) {
    (void)in_sizes; (void)n_in; (void)out_size; (void)ws_size;
    const float* input  = (const float*)d_in[0];
    const float* flow   = (const float*)d_in[1];
    const float* w_node = (const float*)d_in[2];
    const float* b_node = (const float*)d_in[3];
    const float* w_up   = (const float*)d_in[4];
    const float* b_up   = (const float*)d_in[5];
    const float* w_out  = (const float*)d_in[6];
    const float* b_out  = (const float*)d_in[7];
    float* dout = (float*)d_out;

    char* wsb = (char*)d_ws;
    ushort_t* node_bf = (ushort_t*)wsb;                // 2,359,296 B
    ushort_t* w_np    = (ushort_t*)(wsb + 2359296);    //   524,288 B
    ushort_t* wf_p    = (ushort_t*)(wsb + 2883584);    //   524,288 B
    float*    bias_t  = (float*)(wsb + 3407872);       //       256 B

    k_prep<<<256, 256, 0, stream>>>(w_node, w_up, w_out, b_up, b_out, w_np, wf_p, bias_t);
    k_gemm0<<<dim3(144, 4), 256, 0, stream>>>(input, w_np, b_node, node_bf);
    hipFuncSetAttribute(reinterpret_cast<const void*>(k_attn),
                        hipFuncAttributeMaxDynamicSharedMemorySize, ATTN_LDS);
    k_attn<<<576, 256, ATTN_LDS, stream>>>(node_bf, flow, wf_p, bias_t, dout);
}

// Round 7
// 74.621 us; speedup vs baseline: 1.4461x; 1.4461x over previous
//
#include <hip/hip_runtime.h>

// GNN_module: patch-conv -> deformable 27-tap sampling -> per-pixel attention -> up+1x1 conv
// T=8, H=W=24, C=256, K=27, J=216
// R7: R5 structure; k_attn prefetch in NAMED registers (no array -> no scratch spill).

typedef unsigned short ushort_t;
typedef ushort_t ushort8 __attribute__((ext_vector_type(8)));
typedef __bf16 bf16x8 __attribute__((ext_vector_type(8)));
typedef __bf16 bf16x2 __attribute__((ext_vector_type(2)));
typedef float f32x4 __attribute__((ext_vector_type(4)));
typedef unsigned int uint4v __attribute__((ext_vector_type(4)));

#define NSTR 264   // neigh row stride (ushorts)
#define TSTR 34    // neighT row stride (ushorts)
#define ASTR 40    // A_s row stride (ushorts)

// dynamic-LDS byte offsets for k_attn
#define OFF_NH0   0
#define OFF_NH1   16896
#define OFF_NT0   33792
#define OFF_NT1   51200
#define OFF_AS    68608
#define OFF_BASES 69888
#define OFF_WTS   73472
#define ATTN_LDS  77056

__device__ __forceinline__ ushort_t f2bf(float f) {
    __bf16 h = (__bf16)f;
    return __builtin_bit_cast(ushort_t, h);
}
__device__ __forceinline__ float blo(unsigned u) { return __uint_as_float(u << 16); }
__device__ __forceinline__ float bhi(unsigned u) { return __uint_as_float(u & 0xffff0000u); }
__device__ __forceinline__ unsigned pk2(float a, float b) {
    bf16x2 v = { (__bf16)a, (__bf16)b };
    return __builtin_bit_cast(unsigned, v);
}
__device__ __forceinline__ unsigned pk2h(__bf16 a, __bf16 b) {
    bf16x2 v = { a, b };
    return __builtin_bit_cast(unsigned, v);
}
__device__ __forceinline__ void gld_lds16(const void* g, void* l) {
    __builtin_amdgcn_global_load_lds(
        (const __attribute__((address_space(1))) unsigned*)g,
        (__attribute__((address_space(3))) unsigned*)l, 16, 0, 0);
}

// ---------------------------------------------------------------- prep -------
__global__ __launch_bounds__(256) void k_prep(
    const float* __restrict__ w_node, const float* __restrict__ w_up,
    const float* __restrict__ w_out, const float* __restrict__ b_up,
    const float* __restrict__ b_out,
    ushort_t* __restrict__ w_node_perm, ushort_t* __restrict__ Wf_perm,
    float* __restrict__ bias_tot)
{
    __shared__ float wout_s[4096];
    int tid = threadIdx.x;
    for (int i = tid; i < 4096; i += 256) wout_s[i] = w_out[i];
    __syncthreads();
    int gid = blockIdx.x * 256 + tid;
    #pragma unroll
    for (int r = 0; r < 4; ++r) {
        int e = gid + r * 65536;
        {
            int k = e & 1023, n = e >> 10;
            w_node_perm[(((k >> 3) << 8) + n) * 8 + (k & 7)] = f2bf(w_node[n * 1024 + k]);
        }
        {
            int n = e & 1023, k = e >> 10;
            int o = n >> 4, ab = n & 15;
            const float* wo = wout_s + o * 64;
            const float* wu = w_up + (k << 10) + ab;
            float s = 0.f;
            #pragma unroll 8
            for (int c = 0; c < 64; ++c) s += wo[c] * wu[c << 4];
            Wf_perm[(((k >> 3) << 10) + n) * 8 + (k & 7)] = f2bf(s);
        }
    }
    if (blockIdx.x == 0 && tid < 64) {
        float s = b_out[tid];
        const float* wo = wout_s + tid * 64;
        #pragma unroll 8
        for (int c = 0; c < 64; ++c) s += wo[c] * b_up[c];
        bias_tot[tid] = s;
    }
}

// ------------------------------------------------------------ MFMA GEMMs -----
// BM=32, BK=64; NODE: BN=64 (grid 144x4), FINAL: BN=128 (grid 144x8)
template<int FINAL>
__global__ __launch_bounds__(256) void k_gemm(
    const float* __restrict__ input, const ushort_t* __restrict__ a_bf,
    const ushort_t* __restrict__ w_perm, const float* __restrict__ bias,
    ushort_t* __restrict__ node_bf, float* __restrict__ dout)
{
    constexpr int KS = FINAL ? 4 : 16;
    constexpr int N  = FINAL ? 1024 : 256;
    constexpr int BN = FINAL ? 128 : 64;
    constexpr int NI = FINAL ? 2 : 1;
    constexpr int RB = BN / 32;
    __shared__ __align__(16) ushort_t A_lds[2][2048];
    __shared__ __align__(16) ushort_t B_lds[2][BN * 64];
    int tid  = threadIdx.x;
    int lane = tid & 63, wid = tid >> 6;
    int g = lane >> 4, r16 = lane & 15;
    int m0 = blockIdx.x * 32, n0 = blockIdx.y * BN;

    const float*   inpA = nullptr;
    const ushort_t* finA = nullptr;
    int ldsA_slot;
    if constexpr (!FINAL) {
        int mA = tid & 31, kcA = tid >> 5;
        int m = m0 + mA;
        int t = m / 576, hw = m % 576, hh = hw / 24, ww = hw % 24;
        inpA = input + (size_t)(kcA >> 1) * 73728 + t * 9216 + hh * 384 + ww * 4 + (kcA & 1) * 192;
        ldsA_slot = (kcA * 32 + mA) * 8;
    } else {
        int m = m0 + (tid >> 3), q = tid & 7;
        finA = a_bf + m * 256 + ((q ^ (m & 7)) * 8);
        ldsA_slot = tid * 8;
    }

    f32x4 acc[2][NI];
    #pragma unroll
    for (int i = 0; i < 2; ++i)
        #pragma unroll
        for (int j = 0; j < NI; ++j) acc[i][j] = (f32x4){0.f, 0.f, 0.f, 0.f};

    float4 fa, fb;
    #pragma unroll
    for (int r = 0; r < RB; ++r) {
        int s = r * 256 + tid;
        int kc = s / BN, n = s % BN;
        gld_lds16(w_perm + (size_t)((kc * N + n0 + n) * 8), &B_lds[0][s * 8]);
    }
    if constexpr (FINAL) {
        gld_lds16(finA, &A_lds[0][ldsA_slot]);
    } else {
        fa = *(const float4*)(inpA);
        fb = *(const float4*)(inpA + 96);
        uint4v p;
        p.x = pk2(fa.x, fa.y); p.y = pk2(fa.z, fa.w);
        p.z = pk2(fb.x, fb.y); p.w = pk2(fb.z, fb.w);
        *(uint4v*)&A_lds[0][ldsA_slot] = p;
    }
    __syncthreads();

    for (int kb = 0; kb < KS; ++kb) {
        int cur = kb & 1, nxt = cur ^ 1;
        bool more = (kb + 1 < KS);
        if (more) {
            #pragma unroll
            for (int r = 0; r < RB; ++r) {
                int s = r * 256 + tid;
                int kc = s / BN, n = s % BN;
                gld_lds16(w_perm + (size_t)((((kb + 1) * 8 + kc) * N + n0 + n) * 8),
                          &B_lds[nxt][s * 8]);
            }
            if constexpr (FINAL) {
                gld_lds16(finA + (kb + 1) * 64, &A_lds[nxt][ldsA_slot]);
            } else {
                fa = *(const float4*)(inpA + (size_t)(kb + 1) * 294912);
                fb = *(const float4*)(inpA + (size_t)(kb + 1) * 294912 + 96);
            }
        }
        bf16x8 af[2][2], bfr[NI][2];
        #pragma unroll
        for (int mi = 0; mi < 2; ++mi)
            #pragma unroll
            for (int ks = 0; ks < 2; ++ks) {
                int idx;
                if constexpr (!FINAL) idx = ((ks * 4 + g) * 32 + mi * 16 + r16) * 8;
                else                  idx = (mi * 16 + r16) * 64 + (((ks * 4 + g) ^ (r16 & 7)) * 8);
                af[mi][ks] = __builtin_bit_cast(bf16x8, *(const ushort8*)&A_lds[cur][idx]);
            }
        #pragma unroll
        for (int ni = 0; ni < NI; ++ni)
            #pragma unroll
            for (int ks = 0; ks < 2; ++ks) {
                int idx = ((ks * 4 + g) * BN + wid * (BN / 4) + ni * 16 + r16) * 8;
                bfr[ni][ks] = __builtin_bit_cast(bf16x8, *(const ushort8*)&B_lds[cur][idx]);
            }
        #pragma unroll
        for (int mi = 0; mi < 2; ++mi)
            #pragma unroll
            for (int ni = 0; ni < NI; ++ni)
                #pragma unroll
                for (int ks = 0; ks < 2; ++ks)
                    acc[mi][ni] = __builtin_amdgcn_mfma_f32_16x16x32_bf16(
                        af[mi][ks], bfr[ni][ks], acc[mi][ni], 0, 0, 0);
        if constexpr (!FINAL) {
            if (more) {
                uint4v p;
                p.x = pk2(fa.x, fa.y); p.y = pk2(fa.z, fa.w);
                p.z = pk2(fb.x, fb.y); p.w = pk2(fb.z, fb.w);
                *(uint4v*)&A_lds[nxt][ldsA_slot] = p;
            }
        }
        __syncthreads();
    }

    if constexpr (!FINAL) {
        int n = n0 + wid * 16 + r16;
        float bv = bias[n];
        #pragma unroll
        for (int mi = 0; mi < 2; ++mi)
            #pragma unroll
            for (int rr = 0; rr < 4; ++rr) {
                int m = m0 + mi * 16 + 4 * g + rr;
                node_bf[(size_t)m * 256 + n] = f2bf(acc[mi][0][rr] + bv);
            }
    } else {
        #pragma unroll
        for (int ni = 0; ni < NI; ++ni) {
            int n = n0 + wid * 32 + ni * 16 + r16;
            int o = n >> 4, aa = (n >> 2) & 3, bb = n & 3;
            float bv = bias[o];
            #pragma unroll
            for (int mi = 0; mi < 2; ++mi)
                #pragma unroll
                for (int rr = 0; rr < 4; ++rr) {
                    int m = m0 + mi * 16 + 4 * g + rr;
                    int t = m / 576, hw = m % 576, hh = hw / 24, ww = hw % 24;
                    dout[((size_t)(o * 8 + t) * 96 + hh * 4 + aa) * 96 + ww * 4 + bb]
                        = acc[mi][ni][rr] + bv;
                }
        }
    }
}

// ------------------------------------------------------------- attention -----
// One block per position, 4 waves, double-buffered 32-j tiles, 2 barriers/tile.
// Gather prefetch lives in 16 NAMED uint4v registers (64 VGPR) — no scratch.
__device__ __forceinline__ void combine8(
    uint4v t0, uint4v t1, uint4v t2, uint4v t3,
    uint4v t4, uint4v t5, uint4v t6, uint4v t7,
    float4 wA, float4 wB, ushort_t* __restrict__ nh, ushort_t* __restrict__ nt,
    int jl, int c0)
{
    uint4v outA, outB;
    #pragma unroll
    for (int p = 0; p < 4; ++p) {
        unsigned a0 = t0[p], a1 = t1[p], a2 = t2[p], a3 = t3[p];
        unsigned b0 = t4[p], b1 = t5[p], b2 = t6[p], b3 = t7[p];
        float aL = wA.x * blo(a0) + wA.y * blo(a1) + wA.z * blo(a2) + wA.w * blo(a3);
        float aH = wA.x * bhi(a0) + wA.y * bhi(a1) + wA.z * bhi(a2) + wA.w * bhi(a3);
        float bL = wB.x * blo(b0) + wB.y * blo(b1) + wB.z * blo(b2) + wB.w * blo(b3);
        float bH = wB.x * bhi(b0) + wB.y * bhi(b1) + wB.z * bhi(b2) + wB.w * bhi(b3);
        __bf16 cAL = (__bf16)aL, cAH = (__bf16)aH;
        __bf16 cBL = (__bf16)bL, cBH = (__bf16)bH;
        outA[p] = pk2h(cAL, cAH);
        outB[p] = pk2h(cBL, cBH);
        *(unsigned*)(nt + (c0 + 2 * p) * TSTR + jl)     = pk2h(cAL, cBL);
        *(unsigned*)(nt + (c0 + 2 * p + 1) * TSTR + jl) = pk2h(cAH, cBH);
    }
    *(uint4v*)(nh + jl * NSTR + c0)       = outA;
    *(uint4v*)(nh + (jl + 1) * NSTR + c0) = outB;
}

__global__ __launch_bounds__(256) void k_attn(
    const ushort_t* __restrict__ node_bf, const float* __restrict__ flow,
    ushort_t* __restrict__ out_bf)
{
    extern __shared__ char smem[];
    ushort_t* A_s   = (ushort_t*)(smem + OFF_AS);
    int*      bases = (int*)(smem + OFF_BASES);
    float*    wts   = (float*)(smem + OFF_WTS);

    int tid  = threadIdx.x;
    int pos  = blockIdx.x;
    int h    = pos / 24, w = pos % 24;
    int lane = tid & 63, wid = tid >> 6;
    int g    = lane >> 4, r16 = lane & 15;

    if (tid < 224) {
        int j = tid;
        float w00 = 0, w01 = 0, w10 = 0, w11 = 0;
        int b00 = 0, b01 = 0, b10 = 0, b11 = 0;
        if (j < 216) {
            int tt = j / 27, kk = j - tt * 27;
            int d  = 2 * (kk / 9) + 1;
            int oy = (kk / 3) % 3 - 1, ox = kk % 3 - 1;
            float fy = flow[tt * 576 + pos];
            float fx = flow[4608 + tt * 576 + pos];
            float py = (float)(h + oy * d) + fy;
            float px = (float)(w + ox * d) + fx;
            float fy0 = floorf(py), fx0 = floorf(px);
            int y0 = (int)fy0, x0 = (int)fx0;
            float ty = py - fy0, tx = px - fx0;
            int y0c = min(max(y0, 0), 23), y1c = min(max(y0 + 1, 0), 23);
            int x0c = min(max(x0, 0), 23), x1c = min(max(x0 + 1, 0), 23);
            float vy0 = (y0 >= 0 && y0 < 24) ? 1.f : 0.f;
            float vy1 = (y0 >= -1 && y0 < 23) ? 1.f : 0.f;
            float vx0 = (x0 >= 0 && x0 < 24) ? 1.f : 0.f;
            float vx1 = (x0 >= -1 && x0 < 23) ? 1.f : 0.f;
            w00 = (1.f - ty) * (1.f - tx) * vy0 * vx0;
            w01 = (1.f - ty) * tx * vy0 * vx1;
            w10 = ty * (1.f - tx) * vy1 * vx0;
            w11 = ty * tx * vy1 * vx1;
            int base_t = tt * 576 * 256;
            b00 = base_t + (y0c * 24 + x0c) * 256;
            b01 = base_t + (y0c * 24 + x1c) * 256;
            b10 = base_t + (y1c * 24 + x0c) * 256;
            b11 = base_t + (y1c * 24 + x1c) * 256;
        }
        bases[j * 4 + 0] = b00; bases[j * 4 + 1] = b01;
        bases[j * 4 + 2] = b10; bases[j * 4 + 3] = b11;
        wts[j * 4 + 0] = w00; wts[j * 4 + 1] = w01;
        wts[j * 4 + 2] = w10; wts[j * 4 + 3] = w11;
    }
    for (int i = tid; i < 320; i += 256) ((unsigned*)A_s)[i] = 0;

    bf16x8 nbf[8];
    if (wid < 2) {
        int t = r16;
        const ushort_t* src = node_bf + ((size_t)(t & 7) * 576 + pos) * 256 + g * 8;
        ushort8 uz = {};
        #pragma unroll
        for (int s = 0; s < 8; ++s) {
            ushort8 uu = *(const ushort8*)(src + s * 32);
            nbf[s] = __builtin_bit_cast(bf16x8, (t < 8) ? uu : uz);
        }
    }

    f32x4 oacc[4];
    #pragma unroll
    for (int i = 0; i < 4; ++i) oacc[i] = (f32x4){0.f, 0.f, 0.f, 0.f};

    __syncthreads();                             // bases/wts visible

    const int jp2  = (tid >> 4) * 2;             // this thread's j-pair base
    const int c0lo = (tid & 15) * 16;            // low 8-channel block
    const int c0hi = c0lo + 8;

    // 16 named prefetch registers (q=lo/hi channel half x 8 taps)
    uint4v rA0, rA1, rA2, rA3, rA4, rA5, rA6, rA7;
    uint4v rB0, rB1, rB2, rB3, rB4, rB5, rB6, rB7;

    #define PREFETCH(TILE) do {                                   \
        int jA_ = (TILE) * 32 + jp2;                              \
        int4 bsA_ = *(const int4*)&bases[jA_ * 4];                \
        int4 bsB_ = *(const int4*)&bases[jA_ * 4 + 4];            \
        rA0 = *(const uint4v*)(node_bf + bsA_.x + c0lo);          \
        rA1 = *(const uint4v*)(node_bf + bsA_.y + c0lo);          \
        rA2 = *(const uint4v*)(node_bf + bsA_.z + c0lo);          \
        rA3 = *(const uint4v*)(node_bf + bsA_.w + c0lo);          \
        rA4 = *(const uint4v*)(node_bf + bsB_.x + c0lo);          \
        rA5 = *(const uint4v*)(node_bf + bsB_.y + c0lo);          \
        rA6 = *(const uint4v*)(node_bf + bsB_.z + c0lo);          \
        rA7 = *(const uint4v*)(node_bf + bsB_.w + c0lo);          \
        rB0 = *(const uint4v*)(node_bf + bsA_.x + c0hi);          \
        rB1 = *(const uint4v*)(node_bf + bsA_.y + c0hi);          \
        rB2 = *(const uint4v*)(node_bf + bsA_.z + c0hi);          \
        rB3 = *(const uint4v*)(node_bf + bsA_.w + c0hi);          \
        rB4 = *(const uint4v*)(node_bf + bsB_.x + c0hi);          \
        rB5 = *(const uint4v*)(node_bf + bsB_.y + c0hi);          \
        rB6 = *(const uint4v*)(node_bf + bsB_.z + c0hi);          \
        rB7 = *(const uint4v*)(node_bf + bsB_.w + c0hi);          \
    } while (0)

    #define COMBINE(TILE, nh, nt) do {                                          \
        int jC_ = (TILE) * 32 + jp2;                                            \
        float4 wA_ = *(const float4*)&wts[jC_ * 4];                             \
        float4 wB_ = *(const float4*)&wts[jC_ * 4 + 4];                         \
        combine8(rA0, rA1, rA2, rA3, rA4, rA5, rA6, rA7, wA_, wB_, nh, nt, jp2, c0lo); \
        combine8(rB0, rB1, rB2, rB3, rB4, rB5, rB6, rB7, wA_, wB_, nh, nt, jp2, c0hi); \
    } while (0)

    // prologue: fill buffer 0, issue gathers for tile 1
    PREFETCH(0);
    COMBINE(0, (ushort_t*)(smem + OFF_NH0), (ushort_t*)(smem + OFF_NT0));
    PREFETCH(1);
    __syncthreads();

    for (int k = 0; k < 7; ++k) {
        int cur = k & 1;
        ushort_t* nh = (ushort_t*)(smem + (cur ? OFF_NH1 : OFF_NH0));
        ushort_t* nt = (ushort_t*)(smem + (cur ? OFF_NT1 : OFF_NT0));

        // ---- P1: A-GEMM(k) (waves 0,1)
        if (wid < 2) {
            f32x4 aacc = {0.f, 0.f, 0.f, 0.f};
            int jbase = wid * 16;
            #pragma unroll
            for (int s = 0; s < 8; ++s) {
                const ushort_t* bp = nh + (jbase + r16) * NSTR + s * 32 + g * 8;
                bf16x8 bfrag = __builtin_bit_cast(bf16x8, *(const ushort8*)bp);
                aacc = __builtin_amdgcn_mfma_f32_16x16x32_bf16(nbf[s], bfrag, aacc, 0, 0, 0);
            }
            if (g < 2) {
                #pragma unroll
                for (int rr = 0; rr < 4; ++rr)
                    A_s[(4 * g + rr) * ASTR + jbase + r16] = f2bf(aacc[rr] * (1.f / 216.f));
            }
        }
        __syncthreads();

        // ---- P2: out-GEMM(k) || combine(k+1) || prefetch(k+2)
        {
            bf16x8 afrag = __builtin_bit_cast(bf16x8, *(const ushort8*)(A_s + r16 * ASTR + g * 8));
            #pragma unroll
            for (int i = 0; i < 4; ++i) {
                const ushort_t* tp = nt + (wid * 64 + i * 16 + r16) * TSTR + g * 8;
                uint4v uv;
                uv.x = *(const unsigned*)(tp);
                uv.y = *(const unsigned*)(tp + 2);
                uv.z = *(const unsigned*)(tp + 4);
                uv.w = *(const unsigned*)(tp + 6);
                bf16x8 bfrag = __builtin_bit_cast(bf16x8, uv);
                oacc[i] = __builtin_amdgcn_mfma_f32_16x16x32_bf16(afrag, bfrag, oacc[i], 0, 0, 0);
            }
        }
        if (k < 6) {
            ushort_t* nh2 = (ushort_t*)(smem + (cur ? OFF_NH0 : OFF_NH1));
            ushort_t* nt2 = (ushort_t*)(smem + (cur ? OFF_NT0 : OFF_NT1));
            COMBINE(k + 1, nh2, nt2);
            if (k <= 4) PREFETCH(k + 2);
        }
        __syncthreads();
    }
    #undef PREFETCH
    #undef COMBINE

    if (g < 2) {
        #pragma unroll
        for (int i = 0; i < 4; ++i) {
            int c = wid * 64 + i * 16 + r16;
            #pragma unroll
            for (int rr = 0; rr < 4; ++rr) {
                int t = 4 * g + rr;
                out_bf[((size_t)t * 576 + pos) * 256 + c] = f2bf(oacc[i][rr]);
            }
        }
    }
}

// ----------------------------------------------------------------------------
extern "C" void kernel_launch(void* const* d_in, const int* in_sizes, int n_in,
                              void* d_out, int out_size, void* d_ws, size_t ws_size,
                              hipStream_t stream) {
    (void)in_sizes; (void)n_in; (void)out_size; (void)ws_size;
    const float* input  = (const float*)d_in[0];
    const float* flow   = (const float*)d_in[1];
    const float* w_node = (const float*)d_in[2];
    const float* b_node = (const float*)d_in[3];
    const float* w_up   = (const float*)d_in[4];
    const float* b_up   = (const float*)d_in[5];
    const float* w_out  = (const float*)d_in[6];
    const float* b_out  = (const float*)d_in[7];
    float* dout = (float*)d_out;

    char* wsb = (char*)d_ws;
    ushort_t* node_bf = (ushort_t*)wsb;                // 2,359,296 B
    ushort_t* out_bf  = (ushort_t*)(wsb + 2359296);    // 2,359,296 B
    ushort_t* w_np    = (ushort_t*)(wsb + 4718592);    //   524,288 B
    ushort_t* wf_p    = (ushort_t*)(wsb + 5242880);    //   524,288 B
    float*    bias_t  = (float*)(wsb + 5767168);       //       256 B

    k_prep<<<256, 256, 0, stream>>>(w_node, w_up, w_out, b_up, b_out, w_np, wf_p, bias_t);
    k_gemm<0><<<dim3(144, 4), 256, 0, stream>>>(input, nullptr, w_np, b_node, node_bf, nullptr);
    hipFuncSetAttribute(reinterpret_cast<const void*>(k_attn),
                        hipFuncAttributeMaxDynamicSharedMemorySize, ATTN_LDS);
    k_attn<<<576, 256, ATTN_LDS, stream>>>(node_bf, flow, out_bf);
    k_gemm<1><<<dim3(144, 8), 256, 0, stream>>>(nullptr, out_bf, wf_p, bias_t, nullptr, dout);
}

// Round 8
// 64.587 us; speedup vs baseline: 1.6708x; 1.1553x over previous
//
#include <hip/hip_runtime.h>

// GNN_module: patch-conv -> deformable 27-tap sampling -> per-pixel attention -> up+1x1 conv
// T=8, H=W=24, C=256, K=27, J=216
// R8: gemm1 coalesced epilogue (LDS transpose); attn w/o neighT (42KB LDS, 3 blk/CU); prep 4-acc.

typedef unsigned short ushort_t;
typedef ushort_t ushort8 __attribute__((ext_vector_type(8)));
typedef __bf16 bf16x8 __attribute__((ext_vector_type(8)));
typedef __bf16 bf16x2 __attribute__((ext_vector_type(2)));
typedef float f32x4 __attribute__((ext_vector_type(4)));
typedef unsigned int uint4v __attribute__((ext_vector_type(4)));

#define NSTR 264   // neigh row stride (ushorts)
#define ASTR 40    // A_s row stride (ushorts)

// dynamic-LDS byte offsets for k_attn (42,240 B total -> 3 blocks/CU)
#define OFF_NH0   0
#define OFF_NH1   16896
#define OFF_AS    33792
#define OFF_BASES 35072
#define OFF_WTS   38656
#define ATTN_LDS  42240

__device__ __forceinline__ ushort_t f2bf(float f) {
    __bf16 h = (__bf16)f;
    return __builtin_bit_cast(ushort_t, h);
}
__device__ __forceinline__ float blo(unsigned u) { return __uint_as_float(u << 16); }
__device__ __forceinline__ float bhi(unsigned u) { return __uint_as_float(u & 0xffff0000u); }
__device__ __forceinline__ unsigned pk2(float a, float b) {
    bf16x2 v = { (__bf16)a, (__bf16)b };
    return __builtin_bit_cast(unsigned, v);
}
__device__ __forceinline__ void gld_lds16(const void* g, void* l) {
    __builtin_amdgcn_global_load_lds(
        (const __attribute__((address_space(1))) unsigned*)g,
        (__attribute__((address_space(3))) unsigned*)l, 16, 0, 0);
}

// ---------------------------------------------------------------- prep -------
__global__ __launch_bounds__(256) void k_prep(
    const float* __restrict__ w_node, const float* __restrict__ w_up,
    const float* __restrict__ w_out, const float* __restrict__ b_up,
    const float* __restrict__ b_out,
    ushort_t* __restrict__ w_node_perm, ushort_t* __restrict__ Wf_perm,
    float* __restrict__ bias_tot)
{
    __shared__ float wout_s[4096];
    int tid = threadIdx.x;
    for (int i = tid; i < 4096; i += 256) wout_s[i] = w_out[i];
    __syncthreads();
    int gid = blockIdx.x * 256 + tid;
    #pragma unroll
    for (int r = 0; r < 4; ++r) {
        int e = gid + r * 65536;
        {
            int k = e & 1023, n = e >> 10;
            w_node_perm[(((k >> 3) << 8) + n) * 8 + (k & 7)] = f2bf(w_node[n * 1024 + k]);
        }
        {
            int n = e & 1023, k = e >> 10;
            int o = n >> 4, ab = n & 15;
            const float* wo = wout_s + o * 64;
            const float* wu = w_up + (k << 10) + ab;
            float s0 = 0.f, s1 = 0.f, s2 = 0.f, s3 = 0.f;
            #pragma unroll 4
            for (int c = 0; c < 64; c += 4) {
                s0 += wo[c]     * wu[c << 4];
                s1 += wo[c + 1] * wu[(c + 1) << 4];
                s2 += wo[c + 2] * wu[(c + 2) << 4];
                s3 += wo[c + 3] * wu[(c + 3) << 4];
            }
            Wf_perm[(((k >> 3) << 10) + n) * 8 + (k & 7)] = f2bf((s0 + s1) + (s2 + s3));
        }
    }
    if (blockIdx.x == 0 && tid < 64) {
        float s = b_out[tid];
        const float* wo = wout_s + tid * 64;
        #pragma unroll 8
        for (int c = 0; c < 64; ++c) s += wo[c] * b_up[c];
        bias_tot[tid] = s;
    }
}

// ------------------------------------------------------------ MFMA GEMMs -----
// BM=32, BK=64; NODE: BN=64 (grid 144x4), FINAL: BN=128 (grid 144x8)
template<int FINAL>
__global__ __launch_bounds__(256) void k_gemm(
    const float* __restrict__ input, const ushort_t* __restrict__ a_bf,
    const ushort_t* __restrict__ w_perm, const float* __restrict__ bias,
    ushort_t* __restrict__ node_bf, float* __restrict__ dout)
{
    constexpr int KS = FINAL ? 4 : 16;
    constexpr int N  = FINAL ? 1024 : 256;
    constexpr int BN = FINAL ? 128 : 64;
    constexpr int NI = FINAL ? 2 : 1;
    constexpr int RB = BN / 32;
    __shared__ __align__(16) ushort_t A_lds[2][2048];
    __shared__ __align__(16) ushort_t B_lds[2][BN * 64];
    int tid  = threadIdx.x;
    int lane = tid & 63, wid = tid >> 6;
    int g = lane >> 4, r16 = lane & 15;
    int m0 = blockIdx.x * 32, n0 = blockIdx.y * BN;

    const float*   inpA = nullptr;
    const ushort_t* finA = nullptr;
    int ldsA_slot;
    if constexpr (!FINAL) {
        int mA = tid & 31, kcA = tid >> 5;
        int m = m0 + mA;
        int t = m / 576, hw = m % 576, hh = hw / 24, ww = hw % 24;
        inpA = input + (size_t)(kcA >> 1) * 73728 + t * 9216 + hh * 384 + ww * 4 + (kcA & 1) * 192;
        ldsA_slot = (kcA * 32 + mA) * 8;
    } else {
        int m = m0 + (tid >> 3), q = tid & 7;
        finA = a_bf + m * 256 + ((q ^ (m & 7)) * 8);
        ldsA_slot = tid * 8;
    }

    f32x4 acc[2][NI];
    #pragma unroll
    for (int i = 0; i < 2; ++i)
        #pragma unroll
        for (int j = 0; j < NI; ++j) acc[i][j] = (f32x4){0.f, 0.f, 0.f, 0.f};

    float4 fa, fb;
    #pragma unroll
    for (int r = 0; r < RB; ++r) {
        int s = r * 256 + tid;
        int kc = s / BN, n = s % BN;
        gld_lds16(w_perm + (size_t)((kc * N + n0 + n) * 8), &B_lds[0][s * 8]);
    }
    if constexpr (FINAL) {
        gld_lds16(finA, &A_lds[0][ldsA_slot]);
    } else {
        fa = *(const float4*)(inpA);
        fb = *(const float4*)(inpA + 96);
        uint4v p;
        p.x = pk2(fa.x, fa.y); p.y = pk2(fa.z, fa.w);
        p.z = pk2(fb.x, fb.y); p.w = pk2(fb.z, fb.w);
        *(uint4v*)&A_lds[0][ldsA_slot] = p;
    }
    __syncthreads();

    for (int kb = 0; kb < KS; ++kb) {
        int cur = kb & 1, nxt = cur ^ 1;
        bool more = (kb + 1 < KS);
        if (more) {
            #pragma unroll
            for (int r = 0; r < RB; ++r) {
                int s = r * 256 + tid;
                int kc = s / BN, n = s % BN;
                gld_lds16(w_perm + (size_t)((((kb + 1) * 8 + kc) * N + n0 + n) * 8),
                          &B_lds[nxt][s * 8]);
            }
            if constexpr (FINAL) {
                gld_lds16(finA + (kb + 1) * 64, &A_lds[nxt][ldsA_slot]);
            } else {
                fa = *(const float4*)(inpA + (size_t)(kb + 1) * 294912);
                fb = *(const float4*)(inpA + (size_t)(kb + 1) * 294912 + 96);
            }
        }
        bf16x8 af[2][2], bfr[NI][2];
        #pragma unroll
        for (int mi = 0; mi < 2; ++mi)
            #pragma unroll
            for (int ks = 0; ks < 2; ++ks) {
                int idx;
                if constexpr (!FINAL) idx = ((ks * 4 + g) * 32 + mi * 16 + r16) * 8;
                else                  idx = (mi * 16 + r16) * 64 + (((ks * 4 + g) ^ (r16 & 7)) * 8);
                af[mi][ks] = __builtin_bit_cast(bf16x8, *(const ushort8*)&A_lds[cur][idx]);
            }
        #pragma unroll
        for (int ni = 0; ni < NI; ++ni)
            #pragma unroll
            for (int ks = 0; ks < 2; ++ks) {
                int idx = ((ks * 4 + g) * BN + wid * (BN / 4) + ni * 16 + r16) * 8;
                bfr[ni][ks] = __builtin_bit_cast(bf16x8, *(const ushort8*)&B_lds[cur][idx]);
            }
        #pragma unroll
        for (int mi = 0; mi < 2; ++mi)
            #pragma unroll
            for (int ni = 0; ni < NI; ++ni)
                #pragma unroll
                for (int ks = 0; ks < 2; ++ks)
                    acc[mi][ni] = __builtin_amdgcn_mfma_f32_16x16x32_bf16(
                        af[mi][ks], bfr[ni][ks], acc[mi][ni], 0, 0, 0);
        if constexpr (!FINAL) {
            if (more) {
                uint4v p;
                p.x = pk2(fa.x, fa.y); p.y = pk2(fa.z, fa.w);
                p.z = pk2(fb.x, fb.y); p.w = pk2(fb.z, fb.w);
                *(uint4v*)&A_lds[nxt][ldsA_slot] = p;
            }
        }
        __syncthreads();
    }

    if constexpr (!FINAL) {
        int n = n0 + wid * 16 + r16;
        float bv = bias[n];
        #pragma unroll
        for (int mi = 0; mi < 2; ++mi)
            #pragma unroll
            for (int rr = 0; rr < 4; ++rr) {
                int m = m0 + mi * 16 + 4 * g + rr;
                node_bf[(size_t)m * 256 + n] = f2bf(acc[mi][0][rr] + bv);
            }
    } else {
        // coalesced epilogue: acc -> LDS [32][132] f32 -> float4 row stores
        constexpr int EPS = 132;
        float* ep = (float*)&B_lds[0][0];              // 16.9 KB of the 32 KB B_lds
        #pragma unroll
        for (int ni = 0; ni < NI; ++ni) {
            int n = wid * 32 + ni * 16 + r16;
            #pragma unroll
            for (int mi = 0; mi < 2; ++mi)
                #pragma unroll
                for (int rr = 0; rr < 4; ++rr)
                    ep[(mi * 16 + 4 * g + rr) * EPS + n] = acc[mi][ni][rr];
        }
        __syncthreads();
        #pragma unroll
        for (int r = 0; r < 4; ++r) {
            int task = r * 256 + tid;
            int mloc = task & 31, nb4 = task >> 5;     // nb4 in 0..31
            float4 v = *(const float4*)&ep[mloc * EPS + nb4 * 4];
            int n = n0 + nb4 * 4;
            int o = n >> 4, aa = (n >> 2) & 3;
            float bv = bias[o];
            int m = m0 + mloc;
            int t = m / 576, hw = m % 576, hh = hw / 24, ww = hw % 24;
            float* dst = dout + ((size_t)(o * 8 + t) * 96 + hh * 4 + aa) * 96 + ww * 4;
            *(float4*)dst = make_float4(v.x + bv, v.y + bv, v.z + bv, v.w + bv);
        }
    }
}

// ------------------------------------------------------------- attention -----
// One block per position, 4 waves, double-buffered 32-j tiles, 2 barriers/tile.
// Single row-major neigh buffer; out-GEMM B-frags via 8x ds_read_u16 column reads.
__device__ __forceinline__ void combine8(
    uint4v t0, uint4v t1, uint4v t2, uint4v t3,
    uint4v t4, uint4v t5, uint4v t6, uint4v t7,
    float4 wA, float4 wB, ushort_t* __restrict__ nh, int jl, int c0)
{
    uint4v outA, outB;
    #pragma unroll
    for (int p = 0; p < 4; ++p) {
        unsigned a0 = t0[p], a1 = t1[p], a2 = t2[p], a3 = t3[p];
        unsigned b0 = t4[p], b1 = t5[p], b2 = t6[p], b3 = t7[p];
        float aL = wA.x * blo(a0) + wA.y * blo(a1) + wA.z * blo(a2) + wA.w * blo(a3);
        float aH = wA.x * bhi(a0) + wA.y * bhi(a1) + wA.z * bhi(a2) + wA.w * bhi(a3);
        float bL = wB.x * blo(b0) + wB.y * blo(b1) + wB.z * blo(b2) + wB.w * blo(b3);
        float bH = wB.x * bhi(b0) + wB.y * bhi(b1) + wB.z * bhi(b2) + wB.w * bhi(b3);
        outA[p] = pk2(aL, aH);
        outB[p] = pk2(bL, bH);
    }
    *(uint4v*)(nh + jl * NSTR + c0)       = outA;
    *(uint4v*)(nh + (jl + 1) * NSTR + c0) = outB;
}

__global__ __launch_bounds__(256) void k_attn(
    const ushort_t* __restrict__ node_bf, const float* __restrict__ flow,
    ushort_t* __restrict__ out_bf)
{
    extern __shared__ char smem[];
    ushort_t* A_s   = (ushort_t*)(smem + OFF_AS);
    int*      bases = (int*)(smem + OFF_BASES);
    float*    wts   = (float*)(smem + OFF_WTS);

    int tid  = threadIdx.x;
    int pos  = blockIdx.x;
    int h    = pos / 24, w = pos % 24;
    int lane = tid & 63, wid = tid >> 6;
    int g    = lane >> 4, r16 = lane & 15;

    if (tid < 224) {
        int j = tid;
        float w00 = 0, w01 = 0, w10 = 0, w11 = 0;
        int b00 = 0, b01 = 0, b10 = 0, b11 = 0;
        if (j < 216) {
            int tt = j / 27, kk = j - tt * 27;
            int d  = 2 * (kk / 9) + 1;
            int oy = (kk / 3) % 3 - 1, ox = kk % 3 - 1;
            float fy = flow[tt * 576 + pos];
            float fx = flow[4608 + tt * 576 + pos];
            float py = (float)(h + oy * d) + fy;
            float px = (float)(w + ox * d) + fx;
            float fy0 = floorf(py), fx0 = floorf(px);
            int y0 = (int)fy0, x0 = (int)fx0;
            float ty = py - fy0, tx = px - fx0;
            int y0c = min(max(y0, 0), 23), y1c = min(max(y0 + 1, 0), 23);
            int x0c = min(max(x0, 0), 23), x1c = min(max(x0 + 1, 0), 23);
            float vy0 = (y0 >= 0 && y0 < 24) ? 1.f : 0.f;
            float vy1 = (y0 >= -1 && y0 < 23) ? 1.f : 0.f;
            float vx0 = (x0 >= 0 && x0 < 24) ? 1.f : 0.f;
            float vx1 = (x0 >= -1 && x0 < 23) ? 1.f : 0.f;
            w00 = (1.f - ty) * (1.f - tx) * vy0 * vx0;
            w01 = (1.f - ty) * tx * vy0 * vx1;
            w10 = ty * (1.f - tx) * vy1 * vx0;
            w11 = ty * tx * vy1 * vx1;
            int base_t = tt * 576 * 256;
            b00 = base_t + (y0c * 24 + x0c) * 256;
            b01 = base_t + (y0c * 24 + x1c) * 256;
            b10 = base_t + (y1c * 24 + x0c) * 256;
            b11 = base_t + (y1c * 24 + x1c) * 256;
        }
        bases[j * 4 + 0] = b00; bases[j * 4 + 1] = b01;
        bases[j * 4 + 2] = b10; bases[j * 4 + 3] = b11;
        wts[j * 4 + 0] = w00; wts[j * 4 + 1] = w01;
        wts[j * 4 + 2] = w10; wts[j * 4 + 3] = w11;
    }
    for (int i = tid; i < 320; i += 256) ((unsigned*)A_s)[i] = 0;

    bf16x8 nbf[8];
    if (wid < 2) {
        int t = r16;
        const ushort_t* src = node_bf + ((size_t)(t & 7) * 576 + pos) * 256 + g * 8;
        ushort8 uz = {};
        #pragma unroll
        for (int s = 0; s < 8; ++s) {
            ushort8 uu = *(const ushort8*)(src + s * 32);
            nbf[s] = __builtin_bit_cast(bf16x8, (t < 8) ? uu : uz);
        }
    }

    f32x4 oacc[4];
    #pragma unroll
    for (int i = 0; i < 4; ++i) oacc[i] = (f32x4){0.f, 0.f, 0.f, 0.f};

    __syncthreads();                             // bases/wts visible

    const int jp2  = (tid >> 4) * 2;
    const int c0lo = (tid & 15) * 16;
    const int c0hi = c0lo + 8;

    uint4v rA0, rA1, rA2, rA3, rA4, rA5, rA6, rA7;
    uint4v rB0, rB1, rB2, rB3, rB4, rB5, rB6, rB7;

    #define PREFETCH(TILE) do {                                   \
        int jA_ = (TILE) * 32 + jp2;                              \
        int4 bsA_ = *(const int4*)&bases[jA_ * 4];                \
        int4 bsB_ = *(const int4*)&bases[jA_ * 4 + 4];            \
        rA0 = *(const uint4v*)(node_bf + bsA_.x + c0lo);          \
        rA1 = *(const uint4v*)(node_bf + bsA_.y + c0lo);          \
        rA2 = *(const uint4v*)(node_bf + bsA_.z + c0lo);          \
        rA3 = *(const uint4v*)(node_bf + bsA_.w + c0lo);          \
        rA4 = *(const uint4v*)(node_bf + bsB_.x + c0lo);          \
        rA5 = *(const uint4v*)(node_bf + bsB_.y + c0lo);          \
        rA6 = *(const uint4v*)(node_bf + bsB_.z + c0lo);          \
        rA7 = *(const uint4v*)(node_bf + bsB_.w + c0lo);          \
        rB0 = *(const uint4v*)(node_bf + bsA_.x + c0hi);          \
        rB1 = *(const uint4v*)(node_bf + bsA_.y + c0hi);          \
        rB2 = *(const uint4v*)(node_bf + bsA_.z + c0hi);          \
        rB3 = *(const uint4v*)(node_bf + bsA_.w + c0hi);          \
        rB4 = *(const uint4v*)(node_bf + bsB_.x + c0hi);          \
        rB5 = *(const uint4v*)(node_bf + bsB_.y + c0hi);          \
        rB6 = *(const uint4v*)(node_bf + bsB_.z + c0hi);          \
        rB7 = *(const uint4v*)(node_bf + bsB_.w + c0hi);          \
    } while (0)

    #define COMBINE(TILE, nh) do {                                              \
        int jC_ = (TILE) * 32 + jp2;                                            \
        float4 wA_ = *(const float4*)&wts[jC_ * 4];                             \
        float4 wB_ = *(const float4*)&wts[jC_ * 4 + 4];                         \
        combine8(rA0, rA1, rA2, rA3, rA4, rA5, rA6, rA7, wA_, wB_, nh, jp2, c0lo); \
        combine8(rB0, rB1, rB2, rB3, rB4, rB5, rB6, rB7, wA_, wB_, nh, jp2, c0hi); \
    } while (0)

    PREFETCH(0);
    COMBINE(0, (ushort_t*)(smem + OFF_NH0));
    PREFETCH(1);
    __syncthreads();

    for (int k = 0; k < 7; ++k) {
        int cur = k & 1;
        ushort_t* nh = (ushort_t*)(smem + (cur ? OFF_NH1 : OFF_NH0));

        // ---- P1: A-GEMM(k) (waves 0,1)
        if (wid < 2) {
            f32x4 aacc = {0.f, 0.f, 0.f, 0.f};
            int jbase = wid * 16;
            #pragma unroll
            for (int s = 0; s < 8; ++s) {
                const ushort_t* bp = nh + (jbase + r16) * NSTR + s * 32 + g * 8;
                bf16x8 bfrag = __builtin_bit_cast(bf16x8, *(const ushort8*)bp);
                aacc = __builtin_amdgcn_mfma_f32_16x16x32_bf16(nbf[s], bfrag, aacc, 0, 0, 0);
            }
            if (g < 2) {
                #pragma unroll
                for (int rr = 0; rr < 4; ++rr)
                    A_s[(4 * g + rr) * ASTR + jbase + r16] = f2bf(aacc[rr] * (1.f / 216.f));
            }
        }
        __syncthreads();

        // ---- P2: out-GEMM(k) || combine(k+1) || prefetch(k+2)
        {
            bf16x8 afrag = __builtin_bit_cast(bf16x8, *(const ushort8*)(A_s + r16 * ASTR + g * 8));
            #pragma unroll
            for (int i = 0; i < 4; ++i) {
                int cc = wid * 64 + i * 16 + r16;
                ushort8 bv;
                #pragma unroll
                for (int e = 0; e < 8; ++e) bv[e] = nh[(g * 8 + e) * NSTR + cc];
                bf16x8 bfrag = __builtin_bit_cast(bf16x8, bv);
                oacc[i] = __builtin_amdgcn_mfma_f32_16x16x32_bf16(afrag, bfrag, oacc[i], 0, 0, 0);
            }
        }
        if (k < 6) {
            ushort_t* nh2 = (ushort_t*)(smem + (cur ? OFF_NH0 : OFF_NH1));
            COMBINE(k + 1, nh2);
            if (k <= 4) PREFETCH(k + 2);
        }
        __syncthreads();
    }
    #undef PREFETCH
    #undef COMBINE

    if (g < 2) {
        #pragma unroll
        for (int i = 0; i < 4; ++i) {
            int c = wid * 64 + i * 16 + r16;
            #pragma unroll
            for (int rr = 0; rr < 4; ++rr) {
                int t = 4 * g + rr;
                out_bf[((size_t)t * 576 + pos) * 256 + c] = f2bf(oacc[i][rr]);
            }
        }
    }
}

// ----------------------------------------------------------------------------
extern "C" void kernel_launch(void* const* d_in, const int* in_sizes, int n_in,
                              void* d_out, int out_size, void* d_ws, size_t ws_size,
                              hipStream_t stream) {
    (void)in_sizes; (void)n_in; (void)out_size; (void)ws_size;
    const float* input  = (const float*)d_in[0];
    const float* flow   = (const float*)d_in[1];
    const float* w_node = (const float*)d_in[2];
    const float* b_node = (const float*)d_in[3];
    const float* w_up   = (const float*)d_in[4];
    const float* b_up   = (const float*)d_in[5];
    const float* w_out  = (const float*)d_in[6];
    const float* b_out  = (const float*)d_in[7];
    float* dout = (float*)d_out;

    char* wsb = (char*)d_ws;
    ushort_t* node_bf = (ushort_t*)wsb;                // 2,359,296 B
    ushort_t* out_bf  = (ushort_t*)(wsb + 2359296);    // 2,359,296 B
    ushort_t* w_np    = (ushort_t*)(wsb + 4718592);    //   524,288 B
    ushort_t* wf_p    = (ushort_t*)(wsb + 5242880);    //   524,288 B
    float*    bias_t  = (float*)(wsb + 5767168);       //       256 B

    k_prep<<<256, 256, 0, stream>>>(w_node, w_up, w_out, b_up, b_out, w_np, wf_p, bias_t);
    k_gemm<0><<<dim3(144, 4), 256, 0, stream>>>(input, nullptr, w_np, b_node, node_bf, nullptr);
    hipFuncSetAttribute(reinterpret_cast<const void*>(k_attn),
                        hipFuncAttributeMaxDynamicSharedMemorySize, ATTN_LDS);
    k_attn<<<576, 256, ATTN_LDS, stream>>>(node_bf, flow, out_bf);
    k_gemm<1><<<dim3(144, 8), 256, 0, stream>>>(nullptr, out_bf, wf_p, bias_t, nullptr, dout);
}